// Round 3
// baseline (3992.553 us; speedup 1.0000x reference)
//
#include <hip/hip_runtime.h>
#include <hip/hip_bf16.h>
#include <math.h>

typedef __hip_bfloat16 bf16;
typedef unsigned short ushort_t;
typedef unsigned int uint_t;

#define NVTOK 9072
#define BATCH 8
#define LT 32
#define DMODEL 256
#define NHEAD 8
#define DHEAD 32
#define MVIS (BATCH*NVTOK)   /* 72576 */
#define MTEXT (BATCH*LT)     /* 256 */
#define VISSZ 18579456ull    /* MVIS*256 elements */

__device__ __forceinline__ float bf2f(ushort_t u){ return __uint_as_float(((uint_t)u)<<16); }
__device__ __forceinline__ ushort_t f2bfbits(float f){
  __hip_bfloat16 h = __float2bfloat16(f);
  union { __hip_bfloat16 h; ushort_t u; } c; c.h = h; return c.u;
}
// mode: 0 = buffers hold bf16, 1 = buffers hold fp32
__device__ __forceinline__ float ldin(const void* p, size_t i, int mode){
  return mode ? ((const float*)p)[i] : bf2f(((const ushort_t*)p)[i]);
}
__device__ __forceinline__ void stout(void* p, size_t i, int mode, float v){
  if (mode) ((float*)p)[i] = v; else ((ushort_t*)p)[i] = f2bfbits(v);
}

// ---------------------------------------------------------------------------
// D0: dtype detector. Samples dwords of text_tokens. bf16 data -> low 16 bits
// are sane bf16 values; fp32 data -> low 16 bits are random mantissa bits;
// bf16-upcast-to-fp32 -> low 16 bits are exactly zero.
// ---------------------------------------------------------------------------
__global__ void k_detect(const uint_t* __restrict__ buf, int n_avail, int* __restrict__ flag){
  __shared__ int zc, bc;
  if (threadIdx.x==0){ zc=0; bc=0; }
  __syncthreads();
  int stride = n_avail/2048; if (stride < 1) stride = 1;
  int nz=0, nb=0;
  for (int i=threadIdx.x; i<2048; i+=256){
    long long idx = (long long)i*stride;
    if (idx >= n_avail) break;
    uint_t d = buf[idx];
    uint_t lo = d & 0xFFFFu;
    int e = (int)((lo >> 7) & 0xFF);
    if (lo == 0) nz++;
    else if (e >= 90 && e <= 160) nb++;
  }
  atomicAdd(&zc, nz); atomicAdd(&bc, nb);
  __syncthreads();
  if (threadIdx.x==0){
    int mode;
    if (zc > 1024) mode = 1;        // >50% exact-zero low16 -> fp32 (bf16-upcast)
    else if (bc > 1228) mode = 0;   // >60% sane bf16 exponents -> bf16
    else mode = 1;                  // -> fp32
    *flag = mode;
  }
}

// ---------------------------------------------------------------------------
// T1: text prep: off, ref(sigmoid), aw(softmax over L*P=12 per head)
// ---------------------------------------------------------------------------
__global__ __launch_bounds__(256) void k_text_prep(
    const void* text,
    const void* ref_w, const void* ref_b,
    const void* off_w, const void* off_b,
    const void* aw_w,  const void* aw_b,
    float* __restrict__ loc_out, float* __restrict__ aw_out,
    const int* __restrict__ mf)
{
  const int mode = *mf;
  const int r = blockIdx.x;      // 0..255
  const int t = threadIdx.x;
  __shared__ float x[256];
  __shared__ float refv[6];
  __shared__ float offv[192];
  __shared__ float logit[96];
  x[t] = ldin(text, (size_t)r*256 + t, mode);
  __syncthreads();
  if (t < 192) {
    float s = 0.f;
    for (int k=0;k<256;k++) s += x[k]*ldin(off_w, (size_t)k*192+t, mode);
    offv[t] = s + ldin(off_b, t, mode);
  } else if (t < 198) {
    int j = t-192;
    float s = 0.f;
    for (int k=0;k<256;k++) s += x[k]*ldin(ref_w, (size_t)k*6+j, mode);
    s += ldin(ref_b, j, mode);
    refv[j] = 1.f/(1.f+expf(-s));
  }
  if (t < 96) {
    float s = 0.f;
    for (int k=0;k<256;k++) s += x[k]*ldin(aw_w, (size_t)k*96+t, mode);
    logit[t] = s + ldin(aw_b, t, mode);
  }
  __syncthreads();
  if (t < 8) {
    float mx = -1e30f;
    for (int j=0;j<12;j++) mx = fmaxf(mx, logit[t*12+j]);
    float e[12]; float den = 0.f;
    for (int j=0;j<12;j++){ e[j] = expf(logit[t*12+j]-mx); den += e[j]; }
    float inv = 1.f/den;
    for (int j=0;j<12;j++) aw_out[(size_t)r*96 + t*12 + j] = e[j]*inv;
  }
  if (t < 192) {
    int rem = t % 24;
    int l = rem >> 3;
    int c = t & 1;
    const float normW[3] = {96.f,48.f,24.f};
    const float normH[3] = {72.f,36.f,18.f};
    float nrm = (c==0) ? normW[l] : normH[l];
    loc_out[(size_t)r*192 + t] = refv[l*2+c] + offv[t]/nrm;
  }
}

// ---------------------------------------------------------------------------
// T2: deformable sampling, lazy vproj. Masked positions = invalid corners
// (contribute neither sample nor bias, matching reference's zeroed value).
// ---------------------------------------------------------------------------
__global__ __launch_bounds__(64) void k_deform(
    const void* vis_value, const char* __restrict__ vmask,
    const void* vproj_w, const void* vproj_b,
    const float* __restrict__ loc, const float* __restrict__ aw,
    float* __restrict__ ctx_out, const int* __restrict__ mf)
{
  const int mode = *mf;
  const int blk = blockIdx.x;      // r*8 + h
  const int r = blk >> 3;
  const int h = blk & 7;
  const int b = r >> 5;
  const int t = threadIdx.x;       // 0..63, channels 4t..4t+3
  const int Hs[3] = {72,36,18};
  const int Wsz[3] = {96,48,24};
  const int stl[3] = {0,6912,8640};
  float s0=0.f,s1=0.f,s2=0.f,s3=0.f, wsum=0.f;
  for (int l=0;l<3;l++){
    for (int p=0;p<4;p++){
      const int sIdx = blk*12 + l*4 + p;
      const float a  = aw[sIdx];
      const float X = loc[sIdx*2+0]*(float)Wsz[l] - 0.5f;
      const float Y = loc[sIdx*2+1]*(float)Hs[l] - 0.5f;
      const float x0f = floorf(X), y0f = floorf(Y);
      const int x0 = (int)x0f, y0 = (int)y0f;
      const float wx = X-x0f, wy = Y-y0f;
      const float cw[4] = {(1.f-wx)*(1.f-wy), wx*(1.f-wy), (1.f-wx)*wy, wx*wy};
      const int cx[4] = {x0,x0+1,x0,x0+1};
      const int cy[4] = {y0,y0,y0+1,y0+1};
      for (int c=0;c<4;c++){
        if (cx[c]>=0 && cx[c]<Wsz[l] && cy[c]>=0 && cy[c]<Hs[l]){
          const size_t pos = (size_t)b*NVTOK + stl[l] + cy[c]*Wsz[l] + cx[c];
          if (vmask[pos]) continue;   // masked -> projected value is zero
          const float w = a*cw[c];
          wsum += w;
          const size_t base = pos*256 + t*4;
          s0 += w*ldin(vis_value, base+0, mode);
          s1 += w*ldin(vis_value, base+1, mode);
          s2 += w*ldin(vis_value, base+2, mode);
          s3 += w*ldin(vis_value, base+3, mode);
        }
      }
    }
  }
  __shared__ float sh[256];
  sh[t*4+0]=s0; sh[t*4+1]=s1; sh[t*4+2]=s2; sh[t*4+3]=s3;
  __syncthreads();
  if (t < 32) {
    const int col = h*32 + t;
    float acc = wsum * ldin(vproj_b, col, mode);
    for (int k=0;k<256;k++) acc += sh[k]*ldin(vproj_w, (size_t)k*256+col, mode);
    ctx_out[(size_t)r*256 + col] = acc;
  }
}

// block-wide sum of per-thread v (256 threads); all threads get result
__device__ __forceinline__ float block_sum(float v, float* red){
  float sm = v;
  #pragma unroll
  for (int o=32;o>0;o>>=1) sm += __shfl_down(sm,o);
  const int t = threadIdx.x;
  __syncthreads();
  if ((t&63)==0) red[t>>6] = sm;
  __syncthreads();
  return red[0]+red[1]+red[2]+red[3];
}

// ---------------------------------------------------------------------------
// T3: y = ctx@oproj+b ; z = y@lvi_out+b + text ; t_out = LN(z) (two-pass)
// ---------------------------------------------------------------------------
__global__ __launch_bounds__(256) void k_text_attnout(
    const float* __restrict__ ctx,
    const void* oproj_w, const void* oproj_b,
    const void* lvi_out_w, const void* lvi_out_b,
    const void* text, const void* g, const void* be,
    float* __restrict__ t_out, const int* __restrict__ mf)
{
  const int mode = *mf;
  const int r = blockIdx.x; const int t = threadIdx.x;
  __shared__ float x[256]; __shared__ float y[256]; __shared__ float red[4];
  x[t] = ctx[(size_t)r*256+t];
  __syncthreads();
  float s = ldin(oproj_b, t, mode);
  for (int k=0;k<256;k++) s += x[k]*ldin(oproj_w, (size_t)k*256+t, mode);
  y[t] = s;
  __syncthreads();
  float z = ldin(lvi_out_b, t, mode) + ldin(text, (size_t)r*256+t, mode);
  for (int k=0;k<256;k++) z += y[k]*ldin(lvi_out_w, (size_t)k*256+t, mode);
  const float m = block_sum(z, red) * (1.f/256.f);
  __syncthreads();
  const float d = z - m;
  const float var = block_sum(d*d, red) * (1.f/256.f);
  t_out[(size_t)r*256+t] = d*rsqrtf(var+1e-5f)*ldin(g,t,mode) + ldin(be,t,mode);
}

// ---------------------------------------------------------------------------
// T4: ffn = relu(t@f1+b1)@f2+b2 ; text_out = LN(t+ffn) (two-pass)
// ---------------------------------------------------------------------------
__global__ __launch_bounds__(256) void k_text_ffn(
    const float* __restrict__ t_in,
    const void* f1w, const void* f1b,
    const void* f2w, const void* f2b,
    const void* g, const void* be,
    float* __restrict__ tout_f32, void* out_any, const int* __restrict__ mf)
{
  const int mode = *mf;
  const int r = blockIdx.x; const int t = threadIdx.x;
  __shared__ float x[256]; __shared__ float hb[1024]; __shared__ float red[4];
  x[t] = t_in[(size_t)r*256+t];
  __syncthreads();
  for (int j=0;j<4;j++){
    const int col = j*256+t;
    float s = ldin(f1b, col, mode);
    for (int k=0;k<256;k++) s += x[k]*ldin(f1w, (size_t)k*1024+col, mode);
    hb[col] = fmaxf(s,0.f);
  }
  __syncthreads();
  float z = ldin(f2b, t, mode) + x[t];
  for (int k=0;k<1024;k++) z += hb[k]*ldin(f2w, (size_t)k*256+t, mode);
  const float m = block_sum(z, red) * (1.f/256.f);
  __syncthreads();
  const float d = z - m;
  const float var = block_sum(d*d, red) * (1.f/256.f);
  const float o = d*rsqrtf(var+1e-5f)*ldin(g,t,mode) + ldin(be,t,mode);
  tout_f32[(size_t)r*256+t] = o;
  stout(out_any, VISSZ + (size_t)r*256+t, mode, o);
}

// ---------------------------------------------------------------------------
// M1: k/v projection of text_out (256 rows)
// ---------------------------------------------------------------------------
__global__ __launch_bounds__(256) void k_kv_proj(
    const float* __restrict__ tout,
    const void* kw, const void* kb, const void* vw, const void* vb,
    float* __restrict__ kout, float* __restrict__ vout,
    const int* __restrict__ mf)
{
  const int mode = *mf;
  const int r = blockIdx.x; const int t = threadIdx.x;
  __shared__ float x[256];
  x[t] = tout[(size_t)r*256+t];
  __syncthreads();
  float sk = ldin(kb, t, mode);
  float sv = ldin(vb, t, mode);
  for (int k=0;k<256;k++){
    const float xv = x[k];
    sk += xv*ldin(kw, (size_t)k*256+t, mode);
    sv += xv*ldin(vw, (size_t)k*256+t, mode);
  }
  kout[(size_t)r*256+t] = sk;
  vout[(size_t)r*256+t] = sv;
}

// ---------------------------------------------------------------------------
// GEMM: C[M,N] (fp32) = act(A[M,K] @ W[K,N] + bias). A either fp32 ws
// (a_f32=1) or a mode-typed input (a_f32=0). W/bias mode-typed inputs.
// 64x64 tile, BK=32, 256 threads, 4x4/thread. M,N mult of 64, K mult of 32.
// ---------------------------------------------------------------------------
__global__ __launch_bounds__(256) void k_gemm(
    const void* A, size_t a_off, int a_f32,
    const void* W, const void* bias, float* __restrict__ C,
    int M, int N, int K, int relu, const int* __restrict__ mf)
{
  const int mode = *mf;
  __shared__ float As[64][33];
  __shared__ float Bs[32][64];
  const int tid = threadIdx.x;
  const int bm = blockIdx.x, bn = blockIdx.y;
  const int tx = tid & 15, ty = tid >> 4;
  float acc[4][4] = {};
  for (int k0=0;k0<K;k0+=32){
    #pragma unroll
    for (int i=0;i<8;i++){
      const int e = i*256 + tid;
      const int r = e>>5, c = e&31;
      const size_t ai = a_off + (size_t)(bm*64 + r)*K + k0 + c;
      As[r][c] = a_f32 ? ((const float*)A)[ai] : ldin(A, ai, mode);
      const int rb = e>>6, cb = e&63;
      Bs[rb][cb] = ldin(W, (size_t)(k0+rb)*N + bn*64 + cb, mode);
    }
    __syncthreads();
    #pragma unroll
    for (int kk=0;kk<32;kk++){
      const float a0=As[ty*4+0][kk], a1=As[ty*4+1][kk], a2=As[ty*4+2][kk], a3=As[ty*4+3][kk];
      const float b0=Bs[kk][tx*4+0], b1=Bs[kk][tx*4+1], b2=Bs[kk][tx*4+2], b3=Bs[kk][tx*4+3];
      acc[0][0]+=a0*b0; acc[0][1]+=a0*b1; acc[0][2]+=a0*b2; acc[0][3]+=a0*b3;
      acc[1][0]+=a1*b0; acc[1][1]+=a1*b1; acc[1][2]+=a1*b2; acc[1][3]+=a1*b3;
      acc[2][0]+=a2*b0; acc[2][1]+=a2*b1; acc[2][2]+=a2*b2; acc[2][3]+=a2*b3;
      acc[3][0]+=a3*b0; acc[3][1]+=a3*b1; acc[3][2]+=a3*b2; acc[3][3]+=a3*b3;
    }
    __syncthreads();
  }
  const int col0 = bn*64 + tx*4;
  #pragma unroll
  for (int i=0;i<4;i++){
    const size_t ro = (size_t)(bm*64 + ty*4 + i)*N + col0;
    #pragma unroll
    for (int j=0;j<4;j++){
      float v = acc[i][j] + ldin(bias, col0+j, mode);
      if (relu) v = fmaxf(v, 0.f);
      C[ro+j] = v;
    }
  }
}

// ---------------------------------------------------------------------------
// A1: MHA over 32 text keys, fp32 in-place over the chunk's q buffer.
// Blocks of 64 rows may span a batch boundary -> 2-phase LDS load.
// ---------------------------------------------------------------------------
__global__ __launch_bounds__(256) void k_attn(
    float* qc, const float* __restrict__ kws, const float* __restrict__ vws,
    const char* __restrict__ tmask, int r0)
{
  __shared__ float kl[8192];
  __shared__ float vl[8192];
  const int tid = threadIdx.x;
  const int lb = blockIdx.x*64;
  const int b_lo = (r0+lb)/NVTOK;
  const int b_hi = (r0+lb+63)/NVTOK;
  const int nph = (b_hi==b_lo) ? 1 : 2;
  for (int ph=0; ph<nph; ph++){
    const int pb = ph ? b_hi : b_lo;
    __syncthreads();
    for (int i=tid;i<8192;i+=256){
      kl[i] = kws[(size_t)pb*8192+i];
      vl[i] = vws[(size_t)pb*8192+i];
    }
    __syncthreads();
    for (int task=tid; task<512; task+=256){
      const int rr = task>>3, h = task&7;
      const int gr = r0 + lb + rr;
      const int b  = gr / NVTOK;
      if (b != pb) continue;
      float* qp = qc + (size_t)(lb+rr)*256 + h*32;
      float qv[32];
      #pragma unroll
      for (int d=0;d<32;d++) qv[d] = qp[d];
      float sc[32]; float mx = -1e30f;
      #pragma unroll
      for (int k=0;k<32;k++){
        float s;
        if (tmask[b*LT + k]) s = -1e9f;
        else {
          s = 0.f;
          #pragma unroll
          for (int d=0;d<32;d++) s += qv[d]*kl[k*256+h*32+d];
          s *= 0.17677669529663687f;  // 1/sqrt(32)
        }
        sc[k] = s; mx = fmaxf(mx, s);
      }
      float den = 0.f;
      #pragma unroll
      for (int k=0;k<32;k++){ const float e = __expf(sc[k]-mx); sc[k]=e; den+=e; }
      const float inv = 1.f/den;
      float o[32];
      #pragma unroll
      for (int d=0;d<32;d++) o[d] = 0.f;
      #pragma unroll
      for (int k=0;k<32;k++){
        const float w = sc[k]*inv;
        #pragma unroll
        for (int d=0;d<32;d++) o[d] += w*vl[k*256+h*32+d];
      }
      #pragma unroll
      for (int d=0;d<32;d++) qp[d] = o[d];
    }
  }
}

// ---------------------------------------------------------------------------
// residual + two-pass LayerNorm; X fp32; R fp32 ws or mode-typed input;
// OUT fp32 ws (o_f32=1) or final output in mode dtype (o_f32=0).
// ---------------------------------------------------------------------------
__global__ __launch_bounds__(256) void k_add_ln(
    const float* __restrict__ X, const void* R, size_t r_off, int r_f32,
    void* OUT, size_t o_off, int o_f32,
    const void* g, const void* be, const int* __restrict__ mf)
{
  const int mode = *mf;
  const int row = blockIdx.x; const int t = threadIdx.x;
  const size_t idx = (size_t)row*256 + t;
  __shared__ float red[4];
  const float rv = r_f32 ? ((const float*)R)[r_off+idx] : ldin(R, r_off+idx, mode);
  const float v = X[idx] + rv;
  const float m = block_sum(v, red) * (1.f/256.f);
  __syncthreads();
  const float d = v - m;
  const float var = block_sum(d*d, red) * (1.f/256.f);
  const float o = d*rsqrtf(var+1e-5f)*ldin(g,t,mode) + ldin(be,t,mode);
  if (o_f32) ((float*)OUT)[o_off+idx] = o;
  else       stout(OUT, o_off+idx, mode, o);
}

// ---------------------------------------------------------------------------
extern "C" void kernel_launch(void* const* d_in, const int* in_sizes, int n_in,
                              void* d_out, int out_size, void* d_ws, size_t ws_size,
                              hipStream_t stream)
{
  (void)n_in; (void)out_size;
  const void* vis_tokens = d_in[0];
  const void* text_tokens= d_in[1];
  const void* vis_value  = d_in[2];
  const void* ref_w = d_in[3];  const void* ref_b = d_in[4];
  const void* off_w = d_in[5];  const void* off_b = d_in[6];
  const void* aw_w  = d_in[7];  const void* aw_b  = d_in[8];
  const void* vproj_w = d_in[9];  const void* vproj_b = d_in[10];
  const void* oproj_w = d_in[11]; const void* oproj_b = d_in[12];
  const void* lvi_out_w = d_in[13]; const void* lvi_out_b = d_in[14];
  const void* lvi_n1_s = d_in[15];  const void* lvi_n1_b = d_in[16];
  const void* lvi_f1_w = d_in[17];  const void* lvi_f1_b = d_in[18];
  const void* lvi_f2_w = d_in[19];  const void* lvi_f2_b = d_in[20];
  const void* lvi_n2_s = d_in[21];  const void* lvi_n2_b = d_in[22];
  const void* mha_qw = d_in[23]; const void* mha_qb = d_in[24];
  const void* mha_kw = d_in[25]; const void* mha_kb = d_in[26];
  const void* mha_vw = d_in[27]; const void* mha_vb = d_in[28];
  const void* mha_ow = d_in[29]; const void* mha_ob = d_in[30];
  const void* vli_out_w = d_in[31]; const void* vli_out_b = d_in[32];
  const void* vli_n1_s = d_in[33];  const void* vli_n1_b = d_in[34];
  const void* vli_f1_w = d_in[35];  const void* vli_f1_b = d_in[36];
  const void* vli_f2_w = d_in[37];  const void* vli_f2_b = d_in[38];
  const void* vli_n2_s = d_in[39];  const void* vli_n2_b = d_in[40];
  const char* tmask = (const char*)d_in[43];
  const char* vmask = (const char*)d_in[44];

  // ---- workspace layout ----
  char* ws = (char*)d_ws;
  int*   flag    = (int*)  (ws + 0);           // 256 B reserved
  float* loc_ws  = (float*)(ws + 256);         // 196608
  float* aw_ws   = (float*)(ws + 196864);      //  98304
  float* ctxt_ws = (float*)(ws + 295168);      // 262144
  float* t_ws    = (float*)(ws + 557312);      // 262144
  float* tout_ws = (float*)(ws + 819456);      // 262144
  float* k_ws    = (float*)(ws + 1081600);     // 262144
  float* v_ws    = (float*)(ws + 1343744);     // 262144
  const size_t fe = 1605888ull;                // chunk region start

  // chunk rows R: per-row fp32 bytes = qctx 1024 + u 1024 + v1 1024 + h 4096
  long long R_ll = 64;
  if (ws_size > fe) R_ll = (long long)((ws_size - fe) / 7168ull);
  if (R_ll > (long long)MVIS) R_ll = MVIS;
  R_ll &= ~63LL;
  if (R_ll < 64) R_ll = 64;
  const int R = (int)R_ll;
  float* qctx = (float*)(ws + fe);
  float* ubuf = (float*)(ws + fe + (size_t)R*1024ull);
  float* v1b  = (float*)(ws + fe + (size_t)R*2048ull);
  float* hbuf = (float*)(ws + fe + (size_t)R*3072ull);

  // ---- dtype detect (writes flag; everything downstream reads it) ----
  int ndw = in_sizes[1]/2; if (ndw < 1) ndw = 1;
  k_detect<<<1,256,0,stream>>>((const uint_t*)text_tokens, ndw, flag);

  // ---- text side ----
  k_text_prep<<<MTEXT,256,0,stream>>>(text_tokens, ref_w, ref_b, off_w, off_b,
                                      aw_w, aw_b, loc_ws, aw_ws, flag);
  k_deform<<<MTEXT*NHEAD,64,0,stream>>>(vis_value, vmask, vproj_w, vproj_b,
                                        loc_ws, aw_ws, ctxt_ws, flag);
  k_text_attnout<<<MTEXT,256,0,stream>>>(ctxt_ws, oproj_w, oproj_b, lvi_out_w, lvi_out_b,
                                         text_tokens, lvi_n1_s, lvi_n1_b, t_ws, flag);
  k_text_ffn<<<MTEXT,256,0,stream>>>(t_ws, lvi_f1_w, lvi_f1_b, lvi_f2_w, lvi_f2_b,
                                     lvi_n2_s, lvi_n2_b, tout_ws, d_out, flag);
  k_kv_proj<<<MTEXT,256,0,stream>>>(tout_ws, mha_kw, mha_kb, mha_vw, mha_vb,
                                    k_ws, v_ws, flag);

  // ---- vis side, chunked by R rows ----
  for (int r0 = 0; r0 < MVIS; r0 += R){
    const int nr = (MVIS - r0 < R) ? (MVIS - r0) : R;   // multiple of 64
    dim3 gq(nr/64, 4);
    // q = vis_tokens[r0:] @ qw + qb
    k_gemm<<<gq,256,0,stream>>>(vis_tokens, (size_t)r0*256, 0,
                                mha_qw, mha_qb, qctx, nr, 256, 256, 0, flag);
    // ctx = attn(q) in-place
    k_attn<<<nr/64,256,0,stream>>>(qctx, k_ws, v_ws, tmask, r0);
    // u = ctx @ ow + ob
    k_gemm<<<gq,256,0,stream>>>(qctx, 0, 1, mha_ow, mha_ob, ubuf,
                                nr, 256, 256, 0, flag);
    // v1 = LN(u + vis_tokens[r0:])
    k_add_ln<<<nr,256,0,stream>>>(ubuf, vis_tokens, (size_t)r0*256, 0,
                                  v1b, 0, 1, vli_n1_s, vli_n1_b, flag);
    // h = relu(v1 @ f1 + b1)
    dim3 gh(nr/64, 16);
    k_gemm<<<gh,256,0,stream>>>(v1b, 0, 1, vli_f1_w, vli_f1_b, hbuf,
                                nr, 1024, 256, 1, flag);
    // u2 = h @ f2 + b2   (reuse ubuf)
    k_gemm<<<gq,256,0,stream>>>(hbuf, 0, 1, vli_f2_w, vli_f2_b, ubuf,
                                nr, 256, 1024, 0, flag);
    // vis_out[r0:] = LN(u2 + v1)
    k_add_ln<<<nr,256,0,stream>>>(ubuf, v1b, 0, 1,
                                  d_out, (size_t)r0*256, 0, vli_n2_s, vli_n2_b, flag);
  }
}

// Round 4
// 1405.146 us; speedup vs baseline: 2.8414x; 2.8414x over previous
//
#include <hip/hip_runtime.h>
#include <hip/hip_bf16.h>
#include <math.h>

typedef __hip_bfloat16 bf16;
typedef unsigned short ushort_t;
typedef unsigned int uint_t;
typedef short v8s __attribute__((ext_vector_type(8)));
typedef float v4f __attribute__((ext_vector_type(4)));

#define NVTOK 9072
#define BATCH 8
#define LT 32
#define DMODEL 256
#define NHEAD 8
#define DHEAD 32
#define MVIS (BATCH*NVTOK)   /* 72576 */
#define MTEXT (BATCH*LT)     /* 256 */
#define VISSZ 18579456ull    /* MVIS*256 elements */

__device__ __forceinline__ float bf2f(ushort_t u){ return __uint_as_float(((uint_t)u)<<16); }
__device__ __forceinline__ ushort_t f2bfbits(float f){
  __hip_bfloat16 h = __float2bfloat16(f);
  union { __hip_bfloat16 h; ushort_t u; } c; c.h = h; return c.u;
}
// mode: 0 = buffers hold bf16, 1 = buffers hold fp32
__device__ __forceinline__ float ldin(const void* p, size_t i, int mode){
  return mode ? ((const float*)p)[i] : bf2f(((const ushort_t*)p)[i]);
}
__device__ __forceinline__ void stout(void* p, size_t i, int mode, float v){
  if (mode) ((float*)p)[i] = v; else ((ushort_t*)p)[i] = f2bfbits(v);
}

// ---------------------------------------------------------------------------
// D0: dtype detector (unchanged from R3 — verified working)
// ---------------------------------------------------------------------------
__global__ void k_detect(const uint_t* __restrict__ buf, int n_avail, int* __restrict__ flag){
  __shared__ int zc, bc;
  if (threadIdx.x==0){ zc=0; bc=0; }
  __syncthreads();
  int stride = n_avail/2048; if (stride < 1) stride = 1;
  int nz=0, nb=0;
  for (int i=threadIdx.x; i<2048; i+=256){
    long long idx = (long long)i*stride;
    if (idx >= n_avail) break;
    uint_t d = buf[idx];
    uint_t lo = d & 0xFFFFu;
    int e = (int)((lo >> 7) & 0xFF);
    if (lo == 0) nz++;
    else if (e >= 90 && e <= 160) nb++;
  }
  atomicAdd(&zc, nz); atomicAdd(&bc, nb);
  __syncthreads();
  if (threadIdx.x==0){
    int mode;
    if (zc > 1024) mode = 1;
    else if (bc > 1228) mode = 0;
    else mode = 1;
    *flag = mode;
  }
}

// ---------------------------------------------------------------------------
// W-transpose: Wt[n][k] = W[k][n], emitted bf16 (exact round-trip at mode=0).
// grid (K/32, N/32), 256 threads.
// ---------------------------------------------------------------------------
__global__ __launch_bounds__(256) void k_transpose(
    const void* W, ushort_t* __restrict__ Wt, int K, int N,
    const int* __restrict__ mf)
{
  const int mode = *mf;
  __shared__ float tile[32][33];
  const int k0 = blockIdx.x*32, n0 = blockIdx.y*32;
  const int c = threadIdx.x & 31, r8 = threadIdx.x >> 5;
  #pragma unroll
  for (int i=0;i<4;i++){
    const int kk = r8 + i*8;
    tile[kk][c] = ldin(W, (size_t)(k0+kk)*N + n0 + c, mode);
  }
  __syncthreads();
  #pragma unroll
  for (int i=0;i<4;i++){
    const int nn = r8 + i*8;
    Wt[(size_t)(n0+nn)*K + k0 + c] = f2bfbits(tile[c][nn]);
  }
}

// ---------------------------------------------------------------------------
// T1: text prep (unchanged)
// ---------------------------------------------------------------------------
__global__ __launch_bounds__(256) void k_text_prep(
    const void* text,
    const void* ref_w, const void* ref_b,
    const void* off_w, const void* off_b,
    const void* aw_w,  const void* aw_b,
    float* __restrict__ loc_out, float* __restrict__ aw_out,
    const int* __restrict__ mf)
{
  const int mode = *mf;
  const int r = blockIdx.x;
  const int t = threadIdx.x;
  __shared__ float x[256];
  __shared__ float refv[6];
  __shared__ float offv[192];
  __shared__ float logit[96];
  x[t] = ldin(text, (size_t)r*256 + t, mode);
  __syncthreads();
  if (t < 192) {
    float s = 0.f;
    for (int k=0;k<256;k++) s += x[k]*ldin(off_w, (size_t)k*192+t, mode);
    offv[t] = s + ldin(off_b, t, mode);
  } else if (t < 198) {
    int j = t-192;
    float s = 0.f;
    for (int k=0;k<256;k++) s += x[k]*ldin(ref_w, (size_t)k*6+j, mode);
    s += ldin(ref_b, j, mode);
    refv[j] = 1.f/(1.f+expf(-s));
  }
  if (t < 96) {
    float s = 0.f;
    for (int k=0;k<256;k++) s += x[k]*ldin(aw_w, (size_t)k*96+t, mode);
    logit[t] = s + ldin(aw_b, t, mode);
  }
  __syncthreads();
  if (t < 8) {
    float mx = -1e30f;
    for (int j=0;j<12;j++) mx = fmaxf(mx, logit[t*12+j]);
    float e[12]; float den = 0.f;
    for (int j=0;j<12;j++){ e[j] = expf(logit[t*12+j]-mx); den += e[j]; }
    float inv = 1.f/den;
    for (int j=0;j<12;j++) aw_out[(size_t)r*96 + t*12 + j] = e[j]*inv;
  }
  if (t < 192) {
    int rem = t % 24;
    int l = rem >> 3;
    int c = t & 1;
    const float normW[3] = {96.f,48.f,24.f};
    const float normH[3] = {72.f,36.f,18.f};
    float nrm = (c==0) ? normW[l] : normH[l];
    loc_out[(size_t)r*192 + t] = refv[l*2+c] + offv[t]/nrm;
  }
}

// ---------------------------------------------------------------------------
// T2: deformable sampling, lazy vproj (unchanged)
// ---------------------------------------------------------------------------
__global__ __launch_bounds__(64) void k_deform(
    const void* vis_value, const char* __restrict__ vmask,
    const void* vproj_w, const void* vproj_b,
    const float* __restrict__ loc, const float* __restrict__ aw,
    float* __restrict__ ctx_out, const int* __restrict__ mf)
{
  const int mode = *mf;
  const int blk = blockIdx.x;      // r*8 + h
  const int r = blk >> 3;
  const int h = blk & 7;
  const int b = r >> 5;
  const int t = threadIdx.x;
  const int Hs[3] = {72,36,18};
  const int Wsz[3] = {96,48,24};
  const int stl[3] = {0,6912,8640};
  float s0=0.f,s1=0.f,s2=0.f,s3=0.f, wsum=0.f;
  for (int l=0;l<3;l++){
    for (int p=0;p<4;p++){
      const int sIdx = blk*12 + l*4 + p;
      const float a  = aw[sIdx];
      const float X = loc[sIdx*2+0]*(float)Wsz[l] - 0.5f;
      const float Y = loc[sIdx*2+1]*(float)Hs[l] - 0.5f;
      const float x0f = floorf(X), y0f = floorf(Y);
      const int x0 = (int)x0f, y0 = (int)y0f;
      const float wx = X-x0f, wy = Y-y0f;
      const float cw[4] = {(1.f-wx)*(1.f-wy), wx*(1.f-wy), (1.f-wx)*wy, wx*wy};
      const int cx[4] = {x0,x0+1,x0,x0+1};
      const int cy[4] = {y0,y0,y0+1,y0+1};
      for (int c=0;c<4;c++){
        if (cx[c]>=0 && cx[c]<Wsz[l] && cy[c]>=0 && cy[c]<Hs[l]){
          const size_t pos = (size_t)b*NVTOK + stl[l] + cy[c]*Wsz[l] + cx[c];
          if (vmask[pos]) continue;
          const float w = a*cw[c];
          wsum += w;
          const size_t base = pos*256 + t*4;
          s0 += w*ldin(vis_value, base+0, mode);
          s1 += w*ldin(vis_value, base+1, mode);
          s2 += w*ldin(vis_value, base+2, mode);
          s3 += w*ldin(vis_value, base+3, mode);
        }
      }
    }
  }
  __shared__ float sh[256];
  sh[t*4+0]=s0; sh[t*4+1]=s1; sh[t*4+2]=s2; sh[t*4+3]=s3;
  __syncthreads();
  if (t < 32) {
    const int col = h*32 + t;
    float acc = wsum * ldin(vproj_b, col, mode);
    for (int k=0;k<256;k++) acc += sh[k]*ldin(vproj_w, (size_t)k*256+col, mode);
    ctx_out[(size_t)r*256 + col] = acc;
  }
}

__device__ __forceinline__ float block_sum(float v, float* red){
  float sm = v;
  #pragma unroll
  for (int o=32;o>0;o>>=1) sm += __shfl_down(sm,o);
  const int t = threadIdx.x;
  __syncthreads();
  if ((t&63)==0) red[t>>6] = sm;
  __syncthreads();
  return red[0]+red[1]+red[2]+red[3];
}

// ---------------------------------------------------------------------------
// T3: text attn out (unchanged)
// ---------------------------------------------------------------------------
__global__ __launch_bounds__(256) void k_text_attnout(
    const float* __restrict__ ctx,
    const void* oproj_w, const void* oproj_b,
    const void* lvi_out_w, const void* lvi_out_b,
    const void* text, const void* g, const void* be,
    float* __restrict__ t_out, const int* __restrict__ mf)
{
  const int mode = *mf;
  const int r = blockIdx.x; const int t = threadIdx.x;
  __shared__ float x[256]; __shared__ float y[256]; __shared__ float red[4];
  x[t] = ctx[(size_t)r*256+t];
  __syncthreads();
  float s = ldin(oproj_b, t, mode);
  for (int k=0;k<256;k++) s += x[k]*ldin(oproj_w, (size_t)k*256+t, mode);
  y[t] = s;
  __syncthreads();
  float z = ldin(lvi_out_b, t, mode) + ldin(text, (size_t)r*256+t, mode);
  for (int k=0;k<256;k++) z += y[k]*ldin(lvi_out_w, (size_t)k*256+t, mode);
  const float m = block_sum(z, red) * (1.f/256.f);
  __syncthreads();
  const float d = z - m;
  const float var = block_sum(d*d, red) * (1.f/256.f);
  t_out[(size_t)r*256+t] = d*rsqrtf(var+1e-5f)*ldin(g,t,mode) + ldin(be,t,mode);
}

// ---------------------------------------------------------------------------
// T4: text ffn (unchanged)
// ---------------------------------------------------------------------------
__global__ __launch_bounds__(256) void k_text_ffn(
    const float* __restrict__ t_in,
    const void* f1w, const void* f1b,
    const void* f2w, const void* f2b,
    const void* g, const void* be,
    float* __restrict__ tout_f32, void* out_any, const int* __restrict__ mf)
{
  const int mode = *mf;
  const int r = blockIdx.x; const int t = threadIdx.x;
  __shared__ float x[256]; __shared__ float hb[1024]; __shared__ float red[4];
  x[t] = t_in[(size_t)r*256+t];
  __syncthreads();
  for (int j=0;j<4;j++){
    const int col = j*256+t;
    float s = ldin(f1b, col, mode);
    for (int k=0;k<256;k++) s += x[k]*ldin(f1w, (size_t)k*1024+col, mode);
    hb[col] = fmaxf(s,0.f);
  }
  __syncthreads();
  float z = ldin(f2b, t, mode) + x[t];
  for (int k=0;k<1024;k++) z += hb[k]*ldin(f2w, (size_t)k*256+t, mode);
  const float m = block_sum(z, red) * (1.f/256.f);
  __syncthreads();
  const float d = z - m;
  const float var = block_sum(d*d, red) * (1.f/256.f);
  const float o = d*rsqrtf(var+1e-5f)*ldin(g,t,mode) + ldin(be,t,mode);
  tout_f32[(size_t)r*256+t] = o;
  stout(out_any, VISSZ + (size_t)r*256+t, mode, o);
}

// ---------------------------------------------------------------------------
// M1: k/v projection (unchanged)
// ---------------------------------------------------------------------------
__global__ __launch_bounds__(256) void k_kv_proj(
    const float* __restrict__ tout,
    const void* kw, const void* kb, const void* vw, const void* vb,
    float* __restrict__ kout, float* __restrict__ vout,
    const int* __restrict__ mf)
{
  const int mode = *mf;
  const int r = blockIdx.x; const int t = threadIdx.x;
  __shared__ float x[256];
  x[t] = tout[(size_t)r*256+t];
  __syncthreads();
  float sk = ldin(kb, t, mode);
  float sv = ldin(vb, t, mode);
  for (int k=0;k<256;k++){
    const float xv = x[k];
    sk += xv*ldin(kw, (size_t)k*256+t, mode);
    sv += xv*ldin(vw, (size_t)k*256+t, mode);
  }
  kout[(size_t)r*256+t] = sk;
  vout[(size_t)r*256+t] = sv;
}

// ---------------------------------------------------------------------------
// MFMA GEMM: C[M,N] fp32 = act(A @ W + bias). Wt = [N][K] bf16 pre-transposed.
// a_kind=0: raw input (bf16 exact 1-pass at mode 0); a_kind=1: fp32 ws ->
// hi/lo bf16 split, 2 MFMA passes sharing the fp32 accumulator.
// Tile 128x128, BK=32, 256 thr = 4 waves (2x2 of 64x64 quadrants).
// Frag layout (m89/m91-verified): A/B: idx16=lane&15, k=(lane>>4)*8+j;
// C/D: col=lane&15, row=(lane>>4)*4+reg.
// ---------------------------------------------------------------------------
__global__ __launch_bounds__(256) void k_mgemm(
    const void* A, size_t a_off, int a_kind,
    const ushort_t* __restrict__ Wt, const void* bias, float* __restrict__ C,
    int N, int K, int relu, const int* __restrict__ mf)
{
  const int mode = *mf;
  const int split = (a_kind==1) || (mode==1);
  __shared__ ushort_t Ah[128*32];
  __shared__ ushort_t Al[128*32];
  __shared__ ushort_t Bt[128*32];
  const int tid = threadIdx.x;
  const int gm0 = blockIdx.x*128, gn0 = blockIdx.y*128;
  const int wv = tid>>6, lane = tid&63;
  const int mh = (wv&1)*64, nh = (wv>>1)*64;
  const int r16 = lane&15, q8 = (lane>>4)*8;
  const int srow = tid>>1, sseg = (tid&1)*16;
  v4f acc[4][4];
  #pragma unroll
  for (int i=0;i<4;i++)
    #pragma unroll
    for (int j=0;j<4;j++) acc[i][j] = (v4f){0.f,0.f,0.f,0.f};

  for (int k0=0; k0<K; k0+=32){
    if (k0) __syncthreads();
    {
      const ushort_t* src = Wt + (size_t)(gn0+srow)*K + k0 + sseg;
      ((uint4*)&Bt[srow*32+sseg])[0]   = ((const uint4*)src)[0];
      ((uint4*)&Bt[srow*32+sseg+8])[0] = ((const uint4*)src)[1];
    }
    if (!split){
      const ushort_t* src = (const ushort_t*)A + a_off + (size_t)(gm0+srow)*K + k0 + sseg;
      ((uint4*)&Ah[srow*32+sseg])[0]   = ((const uint4*)src)[0];
      ((uint4*)&Ah[srow*32+sseg+8])[0] = ((const uint4*)src)[1];
    } else {
      const float* src = (const float*)A + a_off + (size_t)(gm0+srow)*K + k0 + sseg;
      #pragma unroll
      for (int v=0;v<4;v++){
        float4 f = ((const float4*)src)[v];
        float xs[4] = {f.x, f.y, f.z, f.w};
        #pragma unroll
        for (int e=0;e<4;e++){
          const int idx = srow*32 + sseg + v*4 + e;
          const ushort_t h = f2bfbits(xs[e]);
          Ah[idx] = h;
          Al[idx] = f2bfbits(xs[e] - bf2f(h));
        }
      }
    }
    __syncthreads();
    v8s af[4], bfr[4], al[4];
    #pragma unroll
    for (int mt=0;mt<4;mt++){
      af[mt] = *(const v8s*)&Ah[(mh + mt*16 + r16)*32 + q8];
      if (split) al[mt] = *(const v8s*)&Al[(mh + mt*16 + r16)*32 + q8];
    }
    #pragma unroll
    for (int nt=0;nt<4;nt++)
      bfr[nt] = *(const v8s*)&Bt[(nh + nt*16 + r16)*32 + q8];
    #pragma unroll
    for (int mt=0;mt<4;mt++){
      #pragma unroll
      for (int nt=0;nt<4;nt++){
        acc[mt][nt] = __builtin_amdgcn_mfma_f32_16x16x32_bf16(af[mt], bfr[nt], acc[mt][nt], 0, 0, 0);
        if (split)
          acc[mt][nt] = __builtin_amdgcn_mfma_f32_16x16x32_bf16(al[mt], bfr[nt], acc[mt][nt], 0, 0, 0);
      }
    }
  }
  const int rq = (lane>>4)*4;
  float bv[4];
  #pragma unroll
  for (int nt=0;nt<4;nt++) bv[nt] = ldin(bias, gn0 + nh + nt*16 + r16, mode);
  #pragma unroll
  for (int mt=0;mt<4;mt++){
    #pragma unroll
    for (int r=0;r<4;r++){
      const size_t ro = (size_t)(gm0 + mh + mt*16 + rq + r)*N + gn0 + nh + r16;
      #pragma unroll
      for (int nt=0;nt<4;nt++){
        float v = acc[mt][nt][r] + bv[nt];
        if (relu) v = fmaxf(v, 0.f);
        C[ro + nt*16] = v;
      }
    }
  }
}

// ---------------------------------------------------------------------------
// A1: MHA over 32 text keys (unchanged)
// ---------------------------------------------------------------------------
__global__ __launch_bounds__(256) void k_attn(
    float* qc, const float* __restrict__ kws, const float* __restrict__ vws,
    const char* __restrict__ tmask, int r0)
{
  __shared__ float kl[8192];
  __shared__ float vl[8192];
  const int tid = threadIdx.x;
  const int lb = blockIdx.x*64;
  const int b_lo = (r0+lb)/NVTOK;
  const int b_hi = (r0+lb+63)/NVTOK;
  const int nph = (b_hi==b_lo) ? 1 : 2;
  for (int ph=0; ph<nph; ph++){
    const int pb = ph ? b_hi : b_lo;
    __syncthreads();
    for (int i=tid;i<8192;i+=256){
      kl[i] = kws[(size_t)pb*8192+i];
      vl[i] = vws[(size_t)pb*8192+i];
    }
    __syncthreads();
    for (int task=tid; task<512; task+=256){
      const int rr = task>>3, h = task&7;
      const int gr = r0 + lb + rr;
      const int b  = gr / NVTOK;
      if (b != pb) continue;
      float* qp = qc + (size_t)(lb+rr)*256 + h*32;
      float qv[32];
      #pragma unroll
      for (int d=0;d<32;d++) qv[d] = qp[d];
      float sc[32]; float mx = -1e30f;
      #pragma unroll
      for (int k=0;k<32;k++){
        float s;
        if (tmask[b*LT + k]) s = -1e9f;
        else {
          s = 0.f;
          #pragma unroll
          for (int d=0;d<32;d++) s += qv[d]*kl[k*256+h*32+d];
          s *= 0.17677669529663687f;
        }
        sc[k] = s; mx = fmaxf(mx, s);
      }
      float den = 0.f;
      #pragma unroll
      for (int k=0;k<32;k++){ const float e = __expf(sc[k]-mx); sc[k]=e; den+=e; }
      const float inv = 1.f/den;
      float o[32];
      #pragma unroll
      for (int d=0;d<32;d++) o[d] = 0.f;
      #pragma unroll
      for (int k=0;k<32;k++){
        const float w = sc[k]*inv;
        #pragma unroll
        for (int d=0;d<32;d++) o[d] += w*vl[k*256+h*32+d];
      }
      #pragma unroll
      for (int d=0;d<32;d++) qp[d] = o[d];
    }
  }
}

// ---------------------------------------------------------------------------
// residual + two-pass LayerNorm (unchanged)
// ---------------------------------------------------------------------------
__global__ __launch_bounds__(256) void k_add_ln(
    const float* __restrict__ X, const void* R, size_t r_off, int r_f32,
    void* OUT, size_t o_off, int o_f32,
    const void* g, const void* be, const int* __restrict__ mf)
{
  const int mode = *mf;
  const int row = blockIdx.x; const int t = threadIdx.x;
  const size_t idx = (size_t)row*256 + t;
  __shared__ float red[4];
  const float rv = r_f32 ? ((const float*)R)[r_off+idx] : ldin(R, r_off+idx, mode);
  const float v = X[idx] + rv;
  const float m = block_sum(v, red) * (1.f/256.f);
  __syncthreads();
  const float d = v - m;
  const float var = block_sum(d*d, red) * (1.f/256.f);
  const float o = d*rsqrtf(var+1e-5f)*ldin(g,t,mode) + ldin(be,t,mode);
  if (o_f32) ((float*)OUT)[o_off+idx] = o;
  else       stout(OUT, o_off+idx, mode, o);
}

// ---------------------------------------------------------------------------
extern "C" void kernel_launch(void* const* d_in, const int* in_sizes, int n_in,
                              void* d_out, int out_size, void* d_ws, size_t ws_size,
                              hipStream_t stream)
{
  (void)n_in; (void)out_size;
  const void* vis_tokens = d_in[0];
  const void* text_tokens= d_in[1];
  const void* vis_value  = d_in[2];
  const void* ref_w = d_in[3];  const void* ref_b = d_in[4];
  const void* off_w = d_in[5];  const void* off_b = d_in[6];
  const void* aw_w  = d_in[7];  const void* aw_b  = d_in[8];
  const void* vproj_w = d_in[9];  const void* vproj_b = d_in[10];
  const void* oproj_w = d_in[11]; const void* oproj_b = d_in[12];
  const void* lvi_out_w = d_in[13]; const void* lvi_out_b = d_in[14];
  const void* lvi_n1_s = d_in[15];  const void* lvi_n1_b = d_in[16];
  const void* lvi_f1_w = d_in[17];  const void* lvi_f1_b = d_in[18];
  const void* lvi_f2_w = d_in[19];  const void* lvi_f2_b = d_in[20];
  const void* lvi_n2_s = d_in[21];  const void* lvi_n2_b = d_in[22];
  const void* mha_qw = d_in[23]; const void* mha_qb = d_in[24];
  const void* mha_kw = d_in[25]; const void* mha_kb = d_in[26];
  const void* mha_vw = d_in[27]; const void* mha_vb = d_in[28];
  const void* mha_ow = d_in[29]; const void* mha_ob = d_in[30];
  const void* vli_out_w = d_in[31]; const void* vli_out_b = d_in[32];
  const void* vli_n1_s = d_in[33];  const void* vli_n1_b = d_in[34];
  const void* vli_f1_w = d_in[35];  const void* vli_f1_b = d_in[36];
  const void* vli_f2_w = d_in[37];  const void* vli_f2_b = d_in[38];
  const void* vli_n2_s = d_in[39];  const void* vli_n2_b = d_in[40];
  const char* tmask = (const char*)d_in[43];
  const char* vmask = (const char*)d_in[44];

  // ---- workspace layout ----
  char* ws = (char*)d_ws;
  int*   flag    = (int*)  (ws + 0);               // 256 B
  float* loc_ws  = (float*)(ws + 256);             // 196608
  float* aw_ws   = (float*)(ws + 196864);          //  98304
  float* ctxt_ws = (float*)(ws + 295168);          // 262144
  float* t_ws    = (float*)(ws + 557312);          // 262144
  float* tout_ws = (float*)(ws + 819456);          // 262144
  float* k_ws    = (float*)(ws + 1081600);         // 262144
  float* v_ws    = (float*)(ws + 1343744);         // 262144
  ushort_t* wtq  = (ushort_t*)(ws + 1605888ull);   // 131072 B
  ushort_t* wto  = (ushort_t*)(ws + 1736960ull);   // 131072 B
  ushort_t* wtf1 = (ushort_t*)(ws + 1868032ull);   // 524288 B
  ushort_t* wtf2 = (ushort_t*)(ws + 2392320ull);   // 524288 B
  const size_t fe = 2916608ull;                    // chunk region start

  long long R_ll = 128;
  if (ws_size > fe) R_ll = (long long)((ws_size - fe) / 7168ull);
  if (R_ll > (long long)MVIS) R_ll = MVIS;
  R_ll &= ~127LL;
  if (R_ll < 128) R_ll = 128;
  const int R = (int)R_ll;
  float* qctx = (float*)(ws + fe);
  float* ubuf = (float*)(ws + fe + (size_t)R*1024ull);
  float* v1b  = (float*)(ws + fe + (size_t)R*2048ull);
  float* hbuf = (float*)(ws + fe + (size_t)R*3072ull);

  // ---- dtype detect ----
  int ndw = in_sizes[1]/2; if (ndw < 1) ndw = 1;
  k_detect<<<1,256,0,stream>>>((const uint_t*)text_tokens, ndw, flag);

  // ---- weight transposes for MFMA GEMMs ----
  k_transpose<<<dim3(8,8),  256,0,stream>>>(mha_qw,   wtq,  256, 256,  flag);
  k_transpose<<<dim3(8,8),  256,0,stream>>>(mha_ow,   wto,  256, 256,  flag);
  k_transpose<<<dim3(8,32), 256,0,stream>>>(vli_f1_w, wtf1, 256, 1024, flag);
  k_transpose<<<dim3(32,8), 256,0,stream>>>(vli_f2_w, wtf2, 1024, 256, flag);

  // ---- text side ----
  k_text_prep<<<MTEXT,256,0,stream>>>(text_tokens, ref_w, ref_b, off_w, off_b,
                                      aw_w, aw_b, loc_ws, aw_ws, flag);
  k_deform<<<MTEXT*NHEAD,64,0,stream>>>(vis_value, vmask, vproj_w, vproj_b,
                                        loc_ws, aw_ws, ctxt_ws, flag);
  k_text_attnout<<<MTEXT,256,0,stream>>>(ctxt_ws, oproj_w, oproj_b, lvi_out_w, lvi_out_b,
                                         text_tokens, lvi_n1_s, lvi_n1_b, t_ws, flag);
  k_text_ffn<<<MTEXT,256,0,stream>>>(t_ws, lvi_f1_w, lvi_f1_b, lvi_f2_w, lvi_f2_b,
                                     lvi_n2_s, lvi_n2_b, tout_ws, d_out, flag);
  k_kv_proj<<<MTEXT,256,0,stream>>>(tout_ws, mha_kw, mha_kb, mha_vw, mha_vb,
                                    k_ws, v_ws, flag);

  // ---- vis side, chunked by R rows ----
  for (int r0 = 0; r0 < MVIS; r0 += R){
    const int nr = (MVIS - r0 < R) ? (MVIS - r0) : R;   // multiple of 128
    dim3 g2(nr/128, 2);
    k_mgemm<<<g2,256,0,stream>>>(vis_tokens, (size_t)r0*256, 0,
                                 wtq, mha_qb, qctx, 256, 256, 0, flag);
    k_attn<<<nr/64,256,0,stream>>>(qctx, k_ws, v_ws, tmask, r0);
    k_mgemm<<<g2,256,0,stream>>>(qctx, 0, 1, wto, mha_ob, ubuf, 256, 256, 0, flag);
    k_add_ln<<<nr,256,0,stream>>>(ubuf, vis_tokens, (size_t)r0*256, 0,
                                  v1b, 0, 1, vli_n1_s, vli_n1_b, flag);
    dim3 g8(nr/128, 8);
    k_mgemm<<<g8,256,0,stream>>>(v1b, 0, 1, wtf1, vli_f1_b, hbuf, 1024, 256, 1, flag);
    k_mgemm<<<g2,256,0,stream>>>(hbuf, 0, 1, wtf2, vli_f2_b, ubuf, 256, 1024, 0, flag);
    k_add_ln<<<nr,256,0,stream>>>(ubuf, v1b, 0, 1,
                                  d_out, (size_t)r0*256, 0, vli_n2_s, vli_n2_b, flag);
  }
}